// Round 9
// baseline (67011.877 us; speedup 1.0000x reference)
//
#include <hip/hip_runtime.h>
#include <hip/hip_bf16.h>
#include <hip/hip_cooperative_groups.h>

namespace cg = cooperative_groups;

#define BB 128   // batch
#define LL 512   // seq len
#define HH 2048  // hidden
#define EE 128   // embed
#define VV 96    // vocab
#define BBHH (BB * HH)
#define NBLK 64
#define NTHR 1024
#define GTOT (NBLK * NTHR)

typedef short bf16x8 __attribute__((ext_vector_type(8)));
typedef float f32x4 __attribute__((ext_vector_type(4)));

__device__ __forceinline__ unsigned short f2bf(float f) {
    union { float f; unsigned int u; } c; c.f = f;
    unsigned int u = c.u;
    return (unsigned short)((u + 0x7FFFu + ((u >> 16) & 1u)) >> 16);  // RNE
}

__device__ __forceinline__ unsigned long long ld_dev(const unsigned long long* p) {
    return __hip_atomic_load(p, __ATOMIC_RELAXED, __HIP_MEMORY_SCOPE_AGENT);
}
__device__ __forceinline__ void st_dev(unsigned short* p, unsigned short v) {
    __hip_atomic_store(p, v, __ATOMIC_RELAXED, __HIP_MEMORY_SCOPE_AGENT);
}
__device__ __forceinline__ unsigned ld_dev32(const unsigned* p) {
    return __hip_atomic_load(p, __ATOMIC_RELAXED, __HIP_MEMORY_SCOPE_AGENT);
}
__device__ __forceinline__ void st_dev32(unsigned* p, unsigned v) {
    __hip_atomic_store(p, v, __ATOMIC_RELAXED, __HIP_MEMORY_SCOPE_AGENT);
}

// Contention-free, fence-free slot barrier (R6-proven). sc1 ops bypass the
// non-coherent per-XCD L2s. __syncthreads drains each wave's vmcnt (its sc1
// h-stores are acked at the coherence point) before tid 0 publishes arrival.
// Threads 0..63 (wave 0) busy-poll one slot each.
__device__ __forceinline__ void gridbar(unsigned* slots, unsigned epoch,
                                        int bid, int tid) {
    __syncthreads();
    if (tid == 0) {
        asm volatile("s_waitcnt vmcnt(0)" ::: "memory");
        st_dev32(&slots[bid], epoch);
    }
    if (tid < NBLK) {
        while (ld_dev32(&slots[tid]) < epoch) { /* busy spin */ }
    }
    __syncthreads();
}

// Persistent cooperative RNN, round 9 structure:
//   64 blocks x 1024 threads. Block (bm,bn): rows m0=bm*64 (64 of 128),
//   cols n0=bn*64 (64 of 2048). Wave w = one 16x16 MFMA tile:
//   rt=w&3 (row tile), ct=w>>2 (col tile), global col tile gt=bn*4+ct.
// Changes vs R6/R7 (which pinned at 20-24 us/step):
//   - sc1 h-read volume per step: 64 MB -> 16 MB (each h row read by 32
//     blocks instead of 128).
//   - A-loads batched 16-deep (32 outstanding u64 sc1 loads -> 4 latency
//     exposures per step instead of 8).
//   - W_hh/W_hy pre-packed bf16 fragments streamed from global with NORMAL
//     cached loads (read-only => safe; L2-resident across steps). No LDS.
// Duty waves (gt<6) fuse logits one step behind; across bm=0/1 they cover
// all 128 rows x 96 vocab.
__global__ __launch_bounds__(1024, 4)
void rnn_coop(const int* __restrict__ x, const float* __restrict__ hidden,
              const float* __restrict__ emb, const float* __restrict__ W_xh,
              const float* __restrict__ W_hh, const float* __restrict__ b_h,
              const float* __restrict__ W_hy, const float* __restrict__ b_y,
              float* __restrict__ projE,
              unsigned short* __restrict__ w_hh_frag,
              unsigned short* __restrict__ w_hy_frag,
              unsigned short* __restrict__ hbuf, unsigned* __restrict__ bar,
              float* __restrict__ out_logits, float* __restrict__ out_final)
{
    const int tid  = threadIdx.x;
    const int bid  = blockIdx.x;
    const int gtid = bid * NTHR + tid;

    const int bm = bid >> 5;            // 0..1
    const int bn = bid & 31;            // 0..31
    const int m0 = bm * 64;
    const int n0 = bn * 64;

    // ---- barrier slots = 0 (ws re-poisoned 0xAA before every call) ----
    if (bid == 0 && tid < NBLK) st_dev32(&bar[tid], 0u);

    // ---- W_hh -> fragment-linear bf16 (128 tiles x 32768) ----
    // tile c = i*64+l holds W[tile*16+(l&15)][i*32+(l>>4)*8+j]
    for (int idx = gtid; idx < HH * HH; idx += GTOT) {
        int tile = idx >> 15;
        int rem  = idx & 32767;
        int c    = rem >> 3;
        int j    = rem & 7;
        int l    = c & 63;
        int i    = c >> 6;
        int row  = tile * 16 + (l & 15);
        int k    = i * 32 + (l >> 4) * 8 + j;
        w_hh_frag[idx] = f2bf(W_hh[(size_t)row * HH + k]);
    }
    // ---- W_hy -> fragment-linear bf16 (6 tiles) ----
    for (int idx = gtid; idx < VV * HH; idx += GTOT) {
        int tile = idx >> 15;
        int rem  = idx & 32767;
        int c    = rem >> 3;
        int j    = rem & 7;
        int l    = c & 63;
        int i    = c >> 6;
        int row  = tile * 16 + (l & 15);
        int k    = i * 32 + (l >> 4) * 8 + j;
        w_hy_frag[idx] = f2bf(W_hy[(size_t)row * HH + k]);
    }
    // ---- projE[v][h] = b_h[h] + emb[v][:].W_xh[h][:]  (fp32, exact) ----
    for (int i = gtid; i < VV * HH; i += GTOT) {
        int v  = i >> 11;
        int hc = i & (HH - 1);
        const float4* ep = (const float4*)(emb + (size_t)v * EE);
        const float4* wp = (const float4*)(W_xh + (size_t)hc * EE);
        float s = b_h[hc];
        #pragma unroll 8
        for (int e = 0; e < EE / 4; ++e) {
            float4 a = ep[e], b = wp[e];
            s += a.x * b.x + a.y * b.y + a.z * b.z + a.w * b.w;
        }
        projE[i] = s;
    }
    // ---- h_0 -> bf16 into ping buffer 0 ----
    for (int i = gtid; i < BBHH; i += GTOT) hbuf[i] = f2bf(hidden[i]);

    __syncthreads();
    cg::grid_group grid = cg::this_grid();
    __threadfence();
    grid.sync();   // one-time: publishes setup writes (incl. zeroed slots)

    const int w    = tid >> 6;      // wave 0..15
    const int lane = tid & 63;
    const int col  = lane & 15;
    const int q    = lane >> 4;
    const int rt   = w & 3;                // row tile
    const int ct   = w >> 2;               // col tile within block
    const int am   = m0 + rt * 16 + col;   // A-fragment row (batch index)
    const int n    = n0 + ct * 16 + col;   // output hidden column
    const int gt   = bn * 4 + ct;          // global 16-col tile index 0..127

    const bf16x8* Bp = (const bf16x8*)w_hh_frag + (size_t)gt * 4096 + lane;
    const bool dutyw = (gt < 6);
    const bf16x8* Hp = (const bf16x8*)w_hy_frag + (size_t)gt * 4096 + lane;
    const float by   = dutyw ? b_y[gt * 16 + col] : 0.f;

    // epilogue rows + first-step projE prefetch
    int   mrow[4];
    float pv[4];
    #pragma unroll
    for (int r = 0; r < 4; ++r) {
        mrow[r] = m0 + rt * 16 + q * 4 + r;
        int tok = x[(size_t)mrow[r] * LL];
        pv[r]   = projE[(size_t)tok * HH + n];
    }

    for (int t = 0; t < LL; ++t) {
        const unsigned short* hp = hbuf + (size_t)(t & 1) * BBHH;
        unsigned short* hn       = hbuf + (size_t)((t + 1) & 1) * BBHH;
        const unsigned long long* Ap8 =
            (const unsigned long long*)(hp + (size_t)am * HH) + q * 2;

        f32x4 acc  = {0.f, 0.f, 0.f, 0.f};
        f32x4 accL = {0.f, 0.f, 0.f, 0.f};
        const bool doL = dutyw && (t > 0);

        #pragma unroll
        for (int bi = 0; bi < 4; ++bi) {
            // 16-deep A batch: 32 outstanding sc1 u64 loads
            union { unsigned long long u[2]; bf16x8 v; } A[16];
            #pragma unroll
            for (int j = 0; j < 16; ++j) {
                int i = bi * 16 + j;
                A[j].u[0] = ld_dev(Ap8 + (size_t)i * 8);
                A[j].u[1] = ld_dev(Ap8 + (size_t)i * 8 + 1);
            }
            if (doL) {
                #pragma unroll
                for (int j = 0; j < 16; ++j) {
                    int i = bi * 16 + j;
                    acc  = __builtin_amdgcn_mfma_f32_16x16x32_bf16(A[j].v,
                             Bp[i * 64], acc, 0, 0, 0);
                    accL = __builtin_amdgcn_mfma_f32_16x16x32_bf16(A[j].v,
                             Hp[i * 64], accL, 0, 0, 0);
                }
            } else {
                #pragma unroll
                for (int j = 0; j < 16; ++j) {
                    int i = bi * 16 + j;
                    acc = __builtin_amdgcn_mfma_f32_16x16x32_bf16(A[j].v,
                            Bp[i * 64], acc, 0, 0, 0);
                }
            }
        }

        // h epilogue: C/D layout col=lane&15, row=(lane>>4)*4+r
        #pragma unroll
        for (int r = 0; r < 4; ++r) {
            float v = acc[r] + pv[r];
            v = fminf(fmaxf(v, -15.f), 15.f);
            float e2 = __expf(2.f * v);
            float hv = (e2 - 1.f) / (e2 + 1.f);   // tanh
            st_dev(&hn[(size_t)mrow[r] * HH + n], f2bf(hv));
            if (t == LL - 1) out_final[(size_t)mrow[r] * HH + n] = hv;
        }
        if (doL) {
            #pragma unroll
            for (int r = 0; r < 4; ++r) {
                out_logits[(size_t)mrow[r] * (LL * VV)
                           + (size_t)(t - 1) * VV + gt * 16 + col] = accL[r] + by;
            }
        }
        // prefetch next step's projE values (hides behind barrier)
        if (t + 1 < LL) {
            #pragma unroll
            for (int r = 0; r < 4; ++r) {
                int tok = x[(size_t)mrow[r] * LL + t + 1];
                pv[r]   = projE[(size_t)tok * HH + n];
            }
        }
        gridbar(bar, (unsigned)(t + 1), bid, tid);
    }

    // ---- logits for h_512 -> position 511 (final h is in ping buffer 0) ----
    if (dutyw) {
        const unsigned long long* Ap8 =
            (const unsigned long long*)(hbuf + (size_t)am * HH) + q * 2;
        f32x4 accL = {0.f, 0.f, 0.f, 0.f};
        #pragma unroll
        for (int bi = 0; bi < 4; ++bi) {
            union { unsigned long long u[2]; bf16x8 v; } A[16];
            #pragma unroll
            for (int j = 0; j < 16; ++j) {
                int i = bi * 16 + j;
                A[j].u[0] = ld_dev(Ap8 + (size_t)i * 8);
                A[j].u[1] = ld_dev(Ap8 + (size_t)i * 8 + 1);
            }
            #pragma unroll
            for (int j = 0; j < 16; ++j) {
                int i = bi * 16 + j;
                accL = __builtin_amdgcn_mfma_f32_16x16x32_bf16(A[j].v,
                         Hp[i * 64], accL, 0, 0, 0);
            }
        }
        #pragma unroll
        for (int r = 0; r < 4; ++r) {
            out_logits[(size_t)mrow[r] * (LL * VV)
                       + (size_t)(LL - 1) * VV + gt * 16 + col] = accL[r] + by;
        }
    }
}

extern "C" void kernel_launch(void* const* d_in, const int* in_sizes, int n_in,
                              void* d_out, int out_size, void* d_ws, size_t ws_size,
                              hipStream_t stream) {
    const int*   x      = (const int*)  d_in[0];
    const float* hidden = (const float*)d_in[1];
    const float* emb    = (const float*)d_in[2];
    const float* W_xh   = (const float*)d_in[3];
    const float* W_hh   = (const float*)d_in[4];
    const float* b_h    = (const float*)d_in[5];
    const float* W_hy   = (const float*)d_in[6];
    const float* b_y    = (const float*)d_in[7];

    float* out_logits = (float*)d_out;                          // [B][L][V]
    float* out_final  = out_logits + (size_t)BB * LL * VV;      // [B][H]

    // workspace (~10.3 MB): 8 MB w_hh_frag + 384 KB w_hy_frag + 768 KB projE
    // + 1 MB h ping-pong + barrier slots
    char* ws = (char*)d_ws;
    unsigned short* w_hh_frag = (unsigned short*)ws;                        // 8 MB
    unsigned short* w_hy_frag = (unsigned short*)(ws + 8388608);            // 384 KB
    float* projE              = (float*)(ws + 8388608 + 393216);            // 768 KB
    unsigned short* hbuf      = (unsigned short*)(ws + 8388608 + 393216 + 786432);
    unsigned* bar             = (unsigned*)(ws + 8388608 + 393216 + 786432
                                            + 2 * BBHH * 2);

    void* args[] = { (void*)&x, (void*)&hidden, (void*)&emb, (void*)&W_xh,
                     (void*)&W_hh, (void*)&b_h, (void*)&W_hy, (void*)&b_y,
                     (void*)&projE, (void*)&w_hh_frag, (void*)&w_hy_frag,
                     (void*)&hbuf, (void*)&bar,
                     (void*)&out_logits, (void*)&out_final };
    hipLaunchCooperativeKernel((const void*)rnn_coop, dim3(NBLK), dim3(NTHR),
                               args, 0, stream);
}